// Round 1
// baseline (794.689 us; speedup 1.0000x reference)
//
#include <hip/hip_runtime.h>

typedef __bf16 bf16x8 __attribute__((ext_vector_type(8)));
typedef float f32x4 __attribute__((ext_vector_type(4)));

#define TM 16
#define ROW_F 1029            // floats per x row
#define NKB 33                // 33 * 32 = 1056 padded K
#define LDS_STRIDE 1064       // ushort stride; 1064*2 = 2128 B = 133*16 (odd # of 16B units)

// ---------------- contention row means ----------------
__global__ __launch_bounds__(256) void k_rowmean(const float* __restrict__ cont,
                                                 float* __restrict__ rowmean) {
    __shared__ float red[4];
    int row = blockIdx.x;
    const float4* cr = (const float4*)(cont + (size_t)row * 1024);
    float4 v = cr[threadIdx.x];
    float p = v.x + v.y + v.z + v.w;
    for (int m = 1; m < 64; m <<= 1) p += __shfl_xor(p, m, 64);
    int lane = threadIdx.x & 63, wid = threadIdx.x >> 6;
    if (lane == 0) red[wid] = p;
    __syncthreads();
    if (threadIdx.x == 0)
        rowmean[row] = (red[0] + red[1] + red[2] + red[3]) * (1.0f / 1024.0f);
}

// ---------------- pack w_eff into MFMA B-fragment order ----------------
// w_eff[k] = w1[k] (k<4), w1[k+1] (4<=k<1028), 0 (k>=1028).  K padded to 1056.
// Layout: [(kb*4 + ntile)*64 + lane]*8 + j  -> B[k = kb*32 + (lane>>4)*8 + j][n = ntile*16 + (lane&15)]
__global__ __launch_bounds__(256) void k_wpack(const float* __restrict__ w1,
                                               __bf16* __restrict__ wfrag) {
    int o = blockIdx.x * 256 + threadIdx.x;     // grid sized exactly 67584
    int j    = o & 7;
    int lane = (o >> 3) & 63;
    int nt   = (o >> 9) & 3;
    int kb   = o >> 11;
    int k = kb * 32 + ((lane >> 4) << 3) + j;
    int n = nt * 16 + (lane & 15);
    float val = 0.0f;
    if (k < 4)          val = w1[k * 64 + n];
    else if (k < 1028)  val = w1[(k + 1) * 64 + n];
    wfrag[o] = (__bf16)val;
}

// ---------------- main fused kernel ----------------
__global__ __launch_bounds__(256) void k_main(const float* __restrict__ x,
                                              const float* __restrict__ w1,
                                              const float* __restrict__ b1,
                                              const float* __restrict__ w2,
                                              const float* __restrict__ b2,
                                              const float* __restrict__ w3,
                                              const float* __restrict__ b3,
                                              const float* __restrict__ rowmean,
                                              const __bf16* __restrict__ wfrag,
                                              float* __restrict__ out) {
    __shared__ __align__(16) unsigned short x_lds[TM * LDS_STRIDE];
    __shared__ float h1_lds[TM * 65];   // stride 65 breaks bank aliasing
    __shared__ float ce_lds[TM];

    const int tid  = threadIdx.x;
    const int lane = tid & 63;
    const int w    = tid >> 6;

    // ---- stage 16 full rows: contiguous span, coalesced float4, cvt -> bf16 LDS ----
    const float4* xt = (const float4*)(x + (size_t)blockIdx.x * (TM * ROW_F));
    for (int i = tid; i < (TM * ROW_F) / 4; i += 256) {   // 4116 float4s
        float4 v = xt[i];
        unsigned e = 4u * (unsigned)i;
        unsigned row = e / ROW_F;              // magic-mul const division
        unsigned col = e - row * ROW_F;
        float vv[4] = {v.x, v.y, v.z, v.w};
        #pragma unroll
        for (int jj = 0; jj < 4; ++jj) {
            unsigned c = col + jj, r = row;
            if (c >= ROW_F) { c -= ROW_F; r += 1; }       // float4 may cross a row
            x_lds[r * LDS_STRIDE + c] = __builtin_bit_cast(unsigned short, (__bf16)vv[jj]);
        }
    }
    // zero-pad cols [1029, 1064): MFMA reads k up to 1055; weights there are 0,
    // but LDS garbage could be NaN (NaN*0=NaN) -> must zero.
    for (int i = tid; i < TM * (LDS_STRIDE - ROW_F); i += 256) {
        int r = i / (LDS_STRIDE - ROW_F);
        int c = ROW_F + (i - r * (LDS_STRIDE - ROW_F));
        x_lds[r * LDS_STRIDE + c] = 0;
    }
    __syncthreads();

    // ---- per-row argmax over x cols [4,1028) + contention effect ----
    for (int q = 0; q < 4; ++q) {
        int row = w * 4 + q;
        const unsigned short* rp = &x_lds[row * LDS_STRIDE + 4 + lane * 16];
        float best = -1e30f; int bidx = 4;
        #pragma unroll
        for (int u = 0; u < 4; ++u) {
            ushort4 s4 = *(const ushort4*)(rp + 4 * u);   // 8B-aligned
            unsigned short ss[4] = {s4.x, s4.y, s4.z, s4.w};
            #pragma unroll
            for (int jj = 0; jj < 4; ++jj) {
                float fv = __uint_as_float((unsigned)ss[jj] << 16);  // bf16 -> f32 exact
                int c = 4 + lane * 16 + 4 * u + jj;
                if (fv > best) { best = fv; bidx = c; }
            }
        }
        for (int m = 1; m < 64; m <<= 1) {
            float ov = __shfl_xor(best, m, 64);
            int   oi = __shfl_xor(bidx, m, 64);
            if (ov > best || (ov == best && oi < bidx)) { best = ov; bidx = oi; }
        }
        if (lane == 0) {
            float density = __uint_as_float((unsigned)x_lds[row * LDS_STRIDE] << 16);
            ce_lds[row] = rowmean[bidx - 4] * density;
        }
    }
    __syncthreads();

    // ---- MFMA K-loop: wave w computes h1 tile rows 0..15, cols [w*16, w*16+16) ----
    f32x4 acc = {0.f, 0.f, 0.f, 0.f};
    const float4* wfp = (const float4*)wfrag;
    const unsigned short* abase = &x_lds[(lane & 15) * LDS_STRIDE + ((lane >> 4) << 3)];
    for (int kb = 0; kb < NKB; ++kb) {
        bf16x8 af = *(const bf16x8*)(abase + kb * 32);                 // ds_read_b128
        float4 braw = wfp[(kb * 4 + w) * 64 + lane];                   // coalesced, L2-hot
        bf16x8 bf = __builtin_bit_cast(bf16x8, braw);
        acc = __builtin_amdgcn_mfma_f32_16x16x32_bf16(af, bf, acc, 0, 0, 0);
    }
    // epilogue: C/D layout col = lane&15, row = (lane>>4)*4 + r  [measured m89]
    {
        int n = w * 16 + (lane & 15);
        float w1r4 = w1[4 * 64 + n];
        float bb   = b1[n];
        #pragma unroll
        for (int r = 0; r < 4; ++r) {
            int m = (lane >> 4) * 4 + r;
            float hv = acc[r] + ce_lds[m] * w1r4 + bb;
            h1_lds[m * 65 + n] = fmaxf(hv, 0.0f);
        }
    }
    __syncthreads();

    // ---- layers 2 and 3 in fp32 ----
    {
        int r2 = tid >> 4;       // row 0..15 (= w*4 + (lane>>4))
        int s  = tid & 15;       // 16 threads per row
        int n2 = s * 2;
        float a0 = b2[n2], a1 = b2[n2 + 1];
        const float* hrow = &h1_lds[r2 * 65];
        #pragma unroll 8
        for (int k = 0; k < 64; ++k) {
            float hv = hrow[k];                                   // LDS broadcast
            float2 wv = *(const float2*)(w2 + k * 32 + n2);       // L1-resident
            a0 = fmaf(hv, wv.x, a0);
            a1 = fmaf(hv, wv.y, a1);
        }
        a0 = fmaxf(a0, 0.f); a1 = fmaxf(a1, 0.f);
        float p = a0 * w3[n2] + a1 * w3[n2 + 1];
        p += __shfl_xor(p, 1, 64);
        p += __shfl_xor(p, 2, 64);
        p += __shfl_xor(p, 4, 64);
        p += __shfl_xor(p, 8, 64);
        if (s == 0) out[blockIdx.x * TM + r2] = fmaxf(p + b3[0], 0.f);
    }
}

extern "C" void kernel_launch(void* const* d_in, const int* in_sizes, int n_in,
                              void* d_out, int out_size, void* d_ws, size_t ws_size,
                              hipStream_t stream) {
    const float* x    = (const float*)d_in[0];
    const float* cont = (const float*)d_in[1];
    const float* w1   = (const float*)d_in[2];
    const float* b1   = (const float*)d_in[3];
    const float* w2   = (const float*)d_in[4];
    const float* b2   = (const float*)d_in[5];
    const float* w3   = (const float*)d_in[6];
    const float* b3   = (const float*)d_in[7];

    __bf16* wfrag   = (__bf16*)d_ws;                     // 67584 bf16 = 135168 B
    float*  rowmean = (float*)((char*)d_ws + 135168);    // 1024 f32

    int B = in_sizes[0] / ROW_F;                         // 131072
    float* out = (float*)d_out;

    hipLaunchKernelGGL(k_rowmean, dim3(1024), dim3(256), 0, stream, cont, rowmean);
    hipLaunchKernelGGL(k_wpack,   dim3(264),  dim3(256), 0, stream, w1, wfrag);
    hipLaunchKernelGGL(k_main,    dim3(B / TM), dim3(256), 0, stream,
                       x, w1, b1, w2, b2, w3, b3, rowmean, wfrag, out);
}

// Round 2
// 782.043 us; speedup vs baseline: 1.0162x; 1.0162x over previous
//
#include <hip/hip_runtime.h>

typedef __bf16 bf16x8 __attribute__((ext_vector_type(8)));
typedef float f32x4 __attribute__((ext_vector_type(4)));

#define ROW_F 1029            // floats per x row
#define TMB 64                // rows per block (4 waves x 16 rows)
#define NKB 33                // 33 * 32 = 1056 padded K

// ---------------- contention row means ----------------
__global__ __launch_bounds__(256) void k_rowmean(const float* __restrict__ cont,
                                                 float* __restrict__ rowmean) {
    __shared__ float red[4];
    int row = blockIdx.x;
    const float4* cr = (const float4*)(cont + (size_t)row * 1024);
    float4 v = cr[threadIdx.x];
    float p = v.x + v.y + v.z + v.w;
    for (int m = 1; m < 64; m <<= 1) p += __shfl_xor(p, m, 64);
    int lane = threadIdx.x & 63, wid = threadIdx.x >> 6;
    if (lane == 0) red[wid] = p;
    __syncthreads();
    if (threadIdx.x == 0)
        rowmean[row] = (red[0] + red[1] + red[2] + red[3]) * (1.0f / 1024.0f);
}

// ---------------- pack w_eff into MFMA B-fragment order ----------------
// w_eff[k] = w1[k] (k<4), w1[k+1] (4<=k<1028), 0 (k>=1028).  K padded to 1056.
// Layout: [(kb*4 + ntile)*64 + lane]*8 + j -> B[k = kb*32 + (lane>>4)*8 + j][n = ntile*16 + (lane&15)]
__global__ __launch_bounds__(256) void k_wpack(const float* __restrict__ w1,
                                               __bf16* __restrict__ wfrag) {
    int o = blockIdx.x * 256 + threadIdx.x;     // grid sized exactly 67584
    int j    = o & 7;
    int lane = (o >> 3) & 63;
    int nt   = (o >> 9) & 3;
    int kb   = o >> 11;
    int k = kb * 32 + ((lane >> 4) << 3) + j;
    int n = nt * 16 + (lane & 15);
    float val = 0.0f;
    if (k < 4)          val = w1[k * 64 + n];
    else if (k < 1028)  val = w1[(k + 1) * 64 + n];
    wfrag[o] = (__bf16)val;
}

// ---------------- main fused kernel: register-direct A, fused f32 argmax ----------------
__global__ __launch_bounds__(256, 4) void k_main(const float* __restrict__ x,
                                                 const float* __restrict__ w1,
                                                 const float* __restrict__ b1,
                                                 const float* __restrict__ w2,
                                                 const float* __restrict__ b2,
                                                 const float* __restrict__ w3,
                                                 const float* __restrict__ b3,
                                                 const float* __restrict__ rowmean,
                                                 const __bf16* __restrict__ wfrag,
                                                 float* __restrict__ out) {
    __shared__ float h1_lds[TMB * 65];   // 16.6 KB; stride 65 breaks bank aliasing

    const int tid = threadIdx.x;
    const int l   = tid & 63;
    const int w   = tid >> 6;
    const int m0  = l & 15;              // row within wave tile (A) / col within tile (C)
    const int c   = l >> 4;              // k-partition 0..3

    const int row = blockIdx.x * TMB + w * 16 + m0;
    const float* xr = x + (size_t)row * ROW_F + c * 8;   // lane's k-chunk base
    const f32x4* wfp = (const f32x4*)wfrag;

    f32x4 acc0 = {0.f,0.f,0.f,0.f}, acc1 = {0.f,0.f,0.f,0.f};
    f32x4 acc2 = {0.f,0.f,0.f,0.f}, acc3 = {0.f,0.f,0.f,0.f};
    float best = -1e30f; int bidx = 4; float dens = 0.f;

    // ---- kb = 0 (peeled: k<4 excluded from argmax; capture density) ----
    {
        float v[8];
        #pragma unroll
        for (int j = 0; j < 8; ++j) v[j] = xr[j];
        if (c == 0) dens = v[0];
        bf16x8 af;
        #pragma unroll
        for (int j = 0; j < 8; ++j) {
            af[j] = (__bf16)v[j];
            int k = c * 8 + j;
            bool ok = (k >= 4) && (v[j] > best);
            best = ok ? v[j] : best;
            bidx = ok ? k : bidx;
        }
        acc0 = __builtin_amdgcn_mfma_f32_16x16x32_bf16(af, __builtin_bit_cast(bf16x8, wfp[0*64 + l]), acc0, 0,0,0);
        acc1 = __builtin_amdgcn_mfma_f32_16x16x32_bf16(af, __builtin_bit_cast(bf16x8, wfp[1*64 + l]), acc1, 0,0,0);
        acc2 = __builtin_amdgcn_mfma_f32_16x16x32_bf16(af, __builtin_bit_cast(bf16x8, wfp[2*64 + l]), acc2, 0,0,0);
        acc3 = __builtin_amdgcn_mfma_f32_16x16x32_bf16(af, __builtin_bit_cast(bf16x8, wfp[3*64 + l]), acc3, 0,0,0);
    }

    // ---- kb = 1..31 (no masks) ----
    for (int kb = 1; kb < 32; ++kb) {
        const float* p = xr + kb * 32;
        float v[8];
        #pragma unroll
        for (int j = 0; j < 8; ++j) v[j] = p[j];
        bf16x8 af;
        int kbase = kb * 32 + c * 8;
        #pragma unroll
        for (int j = 0; j < 8; ++j) {
            af[j] = (__bf16)v[j];
            bool gt = v[j] > best;
            best = gt ? v[j] : best;
            bidx = gt ? (kbase + j) : bidx;
        }
        acc0 = __builtin_amdgcn_mfma_f32_16x16x32_bf16(af, __builtin_bit_cast(bf16x8, wfp[(kb*4+0)*64 + l]), acc0, 0,0,0);
        acc1 = __builtin_amdgcn_mfma_f32_16x16x32_bf16(af, __builtin_bit_cast(bf16x8, wfp[(kb*4+1)*64 + l]), acc1, 0,0,0);
        acc2 = __builtin_amdgcn_mfma_f32_16x16x32_bf16(af, __builtin_bit_cast(bf16x8, wfp[(kb*4+2)*64 + l]), acc2, 0,0,0);
        acc3 = __builtin_amdgcn_mfma_f32_16x16x32_bf16(af, __builtin_bit_cast(bf16x8, wfp[(kb*4+3)*64 + l]), acc3, 0,0,0);
    }

    // ---- kb = 32 (peeled: only k=1024..1027 real; k>=1028 contributes zero) ----
    {
        bf16x8 af;
        #pragma unroll
        for (int j = 0; j < 8; ++j) af[j] = (__bf16)0.f;
        if (c == 0) {
            const float* p = xr + 32 * 32;
            #pragma unroll
            for (int j = 0; j < 4; ++j) {
                float v = p[j];
                af[j] = (__bf16)v;
                bool gt = v > best;
                best = gt ? v : best;
                bidx = gt ? (1024 + j) : bidx;
            }
        }
        acc0 = __builtin_amdgcn_mfma_f32_16x16x32_bf16(af, __builtin_bit_cast(bf16x8, wfp[(32*4+0)*64 + l]), acc0, 0,0,0);
        acc1 = __builtin_amdgcn_mfma_f32_16x16x32_bf16(af, __builtin_bit_cast(bf16x8, wfp[(32*4+1)*64 + l]), acc1, 0,0,0);
        acc2 = __builtin_amdgcn_mfma_f32_16x16x32_bf16(af, __builtin_bit_cast(bf16x8, wfp[(32*4+2)*64 + l]), acc2, 0,0,0);
        acc3 = __builtin_amdgcn_mfma_f32_16x16x32_bf16(af, __builtin_bit_cast(bf16x8, wfp[(32*4+3)*64 + l]), acc3, 0,0,0);
    }

    // ---- reduce (best,bidx) across the 4 k-partitions sharing a row ----
    #pragma unroll
    for (int off = 16; off < 64; off <<= 1) {
        float ob = __shfl_xor(best, off, 64);
        int   oi = __shfl_xor(bidx, off, 64);
        if (ob > best || (ob == best && oi < bidx)) { best = ob; bidx = oi; }
    }
    float ce = 0.f;
    if (c == 0) ce = rowmean[bidx - 4] * dens;    // lanes 0..15 hold ce for rows 0..15

    // ce for the C-layout rows this lane owns: m = c*4 + r, held by lane m
    float ce_r[4];
    #pragma unroll
    for (int r = 0; r < 4; ++r) ce_r[r] = __shfl(ce, c * 4 + r, 64);

    // ---- epilogue: h1 = relu(acc + ce*w1[4,:] + b1) -> LDS ----
    {
        const f32x4* accs[4] = {&acc0, &acc1, &acc2, &acc3};
        #pragma unroll
        for (int nt = 0; nt < 4; ++nt) {
            int n = nt * 16 + m0;
            float w14 = w1[4 * 64 + n];
            float bb  = b1[n];
            #pragma unroll
            for (int r = 0; r < 4; ++r) {
                int m = c * 4 + r;
                float hv = (*accs[nt])[r] + ce_r[r] * w14 + bb;
                h1_lds[(w * 16 + m) * 65 + n] = fmaxf(hv, 0.0f);
            }
        }
    }
    __syncthreads();

    // ---- layers 2 and 3 in fp32 (64 rows, 4 sweeps of 16 rows) ----
    {
        int s  = tid & 15;       // 16 threads per row
        int n2 = s * 2;
        #pragma unroll
        for (int it = 0; it < 4; ++it) {
            int r2 = it * 16 + (tid >> 4);
            float a0 = b2[n2], a1 = b2[n2 + 1];
            const float* hrow = &h1_lds[r2 * 65];
            #pragma unroll 8
            for (int k = 0; k < 64; ++k) {
                float hv = hrow[k];                               // LDS broadcast
                float2 wv = *(const float2*)(w2 + k * 32 + n2);   // L1-resident
                a0 = fmaf(hv, wv.x, a0);
                a1 = fmaf(hv, wv.y, a1);
            }
            a0 = fmaxf(a0, 0.f); a1 = fmaxf(a1, 0.f);
            float p = a0 * w3[n2] + a1 * w3[n2 + 1];
            p += __shfl_xor(p, 1, 64);
            p += __shfl_xor(p, 2, 64);
            p += __shfl_xor(p, 4, 64);
            p += __shfl_xor(p, 8, 64);
            if (s == 0) out[blockIdx.x * TMB + r2] = fmaxf(p + b3[0], 0.f);
        }
    }
}

extern "C" void kernel_launch(void* const* d_in, const int* in_sizes, int n_in,
                              void* d_out, int out_size, void* d_ws, size_t ws_size,
                              hipStream_t stream) {
    const float* x    = (const float*)d_in[0];
    const float* cont = (const float*)d_in[1];
    const float* w1   = (const float*)d_in[2];
    const float* b1   = (const float*)d_in[3];
    const float* w2   = (const float*)d_in[4];
    const float* b2   = (const float*)d_in[5];
    const float* w3   = (const float*)d_in[6];
    const float* b3   = (const float*)d_in[7];

    __bf16* wfrag   = (__bf16*)d_ws;                     // 67584 bf16 = 135168 B
    float*  rowmean = (float*)((char*)d_ws + 135168);    // 1024 f32

    int B = in_sizes[0] / ROW_F;                         // 131072
    float* out = (float*)d_out;

    hipLaunchKernelGGL(k_rowmean, dim3(1024),    dim3(256), 0, stream, cont, rowmean);
    hipLaunchKernelGGL(k_wpack,   dim3(264),     dim3(256), 0, stream, w1, wfrag);
    hipLaunchKernelGGL(k_main,    dim3(B / TMB), dim3(256), 0, stream,
                       x, w1, b1, w2, b2, w3, b3, rowmean, wfrag, out);
}